// Round 1
// baseline (1423.393 us; speedup 1.0000x reference)
//
#include <hip/hip_runtime.h>
#include <math.h>
#include <float.h>

// Problem constants
#define N_SEQ 2048
#define DIMN  1024
#define NH    16
#define DH    64
#define ROT   32
#define MEM   16
#define JTOT  (N_SEQ + MEM)   // 2064
#define NB    32              // rel-pos buckets
#define REL_SCALE 8.0f        // sqrt(DH)
#define C_SPLIT 4
#define JS      516           // JTOT / C_SPLIT

// ---------------------------------------------------------------------------
// Generic fp32 GEMM: C = A(MxK) @ B(KxN) (+bias). 64x64 tile, BK=16, 4x4/thread.
// ---------------------------------------------------------------------------
__global__ __launch_bounds__(256) void gemm_f32(
    const float* __restrict__ A, const float* __restrict__ B,
    float* __restrict__ C, const float* __restrict__ bias,
    int M, int K, int N)
{
  __shared__ float As[16][68];   // transposed, padded
  __shared__ float Bs[16][64];
  const int tid = threadIdx.x;
  const int tx = tid & 15, ty = tid >> 4;
  const int m0 = blockIdx.y * 64, n0 = blockIdx.x * 64;
  const int la_r = tid >> 2;           // 0..63
  const int la_k = (tid & 3) * 4;      // 0,4,8,12
  const int lb_k = tid >> 4;           // 0..15
  const int lb_n = (tid & 15) * 4;
  float acc[4][4] = {};
  for (int k0 = 0; k0 < K; k0 += 16) {
    float4 av = *(const float4*)&A[(size_t)(m0 + la_r) * K + k0 + la_k];
    float4 bv = *(const float4*)&B[(size_t)(k0 + lb_k) * N + n0 + lb_n];
    __syncthreads();
    As[la_k + 0][la_r] = av.x;
    As[la_k + 1][la_r] = av.y;
    As[la_k + 2][la_r] = av.z;
    As[la_k + 3][la_r] = av.w;
    *(float4*)&Bs[lb_k][lb_n] = bv;
    __syncthreads();
#pragma unroll
    for (int kk = 0; kk < 16; ++kk) {
      float4 a = *(const float4*)&As[kk][ty * 4];
      float4 b = *(const float4*)&Bs[kk][tx * 4];
      acc[0][0] += a.x * b.x; acc[0][1] += a.x * b.y; acc[0][2] += a.x * b.z; acc[0][3] += a.x * b.w;
      acc[1][0] += a.y * b.x; acc[1][1] += a.y * b.y; acc[1][2] += a.y * b.z; acc[1][3] += a.y * b.w;
      acc[2][0] += a.z * b.x; acc[2][1] += a.z * b.y; acc[2][2] += a.z * b.z; acc[2][3] += a.z * b.w;
      acc[3][0] += a.w * b.x; acc[3][1] += a.w * b.y; acc[3][2] += a.w * b.z; acc[3][3] += a.w * b.w;
    }
  }
  float4 bb = make_float4(0.f, 0.f, 0.f, 0.f);
  if (bias) bb = *(const float4*)&bias[n0 + tx * 4];
#pragma unroll
  for (int r = 0; r < 4; ++r) {
    float4 o = make_float4(acc[r][0] + bb.x, acc[r][1] + bb.y,
                           acc[r][2] + bb.z, acc[r][3] + bb.w);
    *(float4*)&C[(size_t)(m0 + ty * 4 + r) * N + n0 + tx * 4] = o;
  }
}

// ---------------------------------------------------------------------------
// Rotary + l2norm + layout: tmp[3][N][DIM] -> qb[h][i][d], kb/vb[h][j][d]
// (memory slots j<16 from mem_k/mem_v; mem_k l2-normalized, not rotated).
// One wave per row.
// ---------------------------------------------------------------------------
__global__ __launch_bounds__(256) void postproc(
    const float* __restrict__ tmp, const float* __restrict__ rot,
    const float* __restrict__ mem_k, const float* __restrict__ mem_v,
    float* __restrict__ qb, float* __restrict__ kb, float* __restrict__ vb)
{
  const int gw = (blockIdx.x * 256 + threadIdx.x) >> 6;
  const int lane = threadIdx.x & 63;
  const int TQ = NH * N_SEQ;
  if (gw < TQ) {
    const int h = gw >> 11;       // / N_SEQ
    const int i = gw & (N_SEQ - 1);
    const size_t base = (size_t)i * DIMN + h * DH + lane;
    float q = tmp[base];
    float k = tmp[base + (size_t)N_SEQ * DIMN];
    float v = tmp[base + 2 * (size_t)N_SEQ * DIMN];
    float cf = 1.f, sf = 0.f;
    if (lane < ROT) { float f = rot[(size_t)i * ROT + lane]; cf = cosf(f); sf = sinf(f); }
    float qp = __shfl_xor(q, 16);
    float kp = __shfl_xor(k, 16);
    float vp = __shfl_xor(v, 16);
    if (lane < ROT) {
      float sgn = (lane < 16) ? -1.f : 1.f;
      q = q * cf + sgn * qp * sf;
      k = k * cf + sgn * kp * sf;
      v = v * cf + sgn * vp * sf;
    }
    float nq = q * q, nk = k * k;
#pragma unroll
    for (int off = 32; off; off >>= 1) { nq += __shfl_xor(nq, off); nk += __shfl_xor(nk, off); }
    q *= 1.f / fmaxf(sqrtf(nq), 1e-12f);
    k *= 1.f / fmaxf(sqrtf(nk), 1e-12f);
    qb[((size_t)h * N_SEQ + i) * DH + lane] = q;
    kb[((size_t)h * JTOT + MEM + i) * DH + lane] = k;
    vb[((size_t)h * JTOT + MEM + i) * DH + lane] = v;
  } else if (gw < TQ + NH * MEM) {
    const int r = gw - TQ;
    const int h = r >> 4, mm = r & 15;
    float k = mem_k[((size_t)h * MEM + mm) * DH + lane];
    float v = mem_v[((size_t)h * MEM + mm) * DH + lane];
    float nk = k * k;
#pragma unroll
    for (int off = 32; off; off >>= 1) nk += __shfl_xor(nk, off);
    k *= 1.f / fmaxf(sqrtf(nk), 1e-12f);
    kb[((size_t)h * JTOT + mm) * DH + lane] = k;
    vb[((size_t)h * JTOT + mm) * DH + lane] = v;
  }
}

// rel-pos bucket (mirrors the f32 reference formula)
__device__ __forceinline__ int rel_bucket(int n) {
  if (n < 0) n = 0;
  if (n < 16) return n;
  int v = 16 + (int)(logf((float)n * 0.0625f) * 7.6944042f);  // 16/ln(8)
  return v > 31 ? 31 : v;
}

// ---------------------------------------------------------------------------
// Pass 1: partial (m,l) per (h1, i) per j-split. Block = 16 queries x 16 heads.
// ---------------------------------------------------------------------------
#define JB1 8
__global__ __launch_bounds__(256) void attn_pass1(
    const float* __restrict__ qb, const float* __restrict__ kb,
    const float* __restrict__ pre_proj, const float* __restrict__ qk_scale,
    const float* __restrict__ rel_table,
    float* __restrict__ mpart, float* __restrict__ lpart)
{
  const int i0 = blockIdx.x * 16;
  const int c = blockIdx.y;
  const int jlo = c * JS;
  if (jlo >= i0 + 32) return;                 // whole split masked for this tile
  const int jhi = min(jlo + JS, i0 + 32);
  const int tid = threadIdx.x;
  const int ii = tid & 15, h = tid >> 4;
  const int i = i0 + ii;

  __shared__ float k_lds[JB1][NH][DH + 4];
  __shared__ float sc[JB1][NH][16];
  __shared__ float pre[NH][NH];
  __shared__ float relt[NB][NH];
  __shared__ float scl[NH];

  pre[tid >> 4][tid & 15] = pre_proj[tid];
  for (int t = tid; t < NB * NH; t += 256) relt[t >> 4][t & 15] = rel_table[t];
  if (tid < NH) scl[tid] = 1.0f / fmaxf(expf(qk_scale[tid]), 0.01f);

  float4 qr[16];
  {
    const float4* qrow = (const float4*)(qb + ((size_t)h * N_SEQ + i) * DH);
#pragma unroll
    for (int t = 0; t < 16; ++t) qr[t] = qrow[t];
  }
  float m = -FLT_MAX, l = 0.0f;
  __syncthreads();

  for (int jb = jlo; jb < jhi; jb += JB1) {
    {
      const int hl = tid >> 4;
      const int x4 = (tid & 15) * 4;
#pragma unroll
      for (int w = 0; w < JB1; ++w) {
        int jg = jb + w; if (jg > JTOT - 1) jg = JTOT - 1;
        *(float4*)&k_lds[w][hl][x4] =
            *(const float4*)(kb + ((size_t)hl * JTOT + jg) * DH + x4);
      }
    }
    __syncthreads();
#pragma unroll
    for (int jj = 0; jj < JB1; ++jj) {
      const float* kr = k_lds[jj][h];
      float acc = 0.f;
#pragma unroll
      for (int t = 0; t < 16; ++t) {
        float4 kv = *(const float4*)&kr[t * 4];
        acc += qr[t].x * kv.x + qr[t].y * kv.y + qr[t].z * kv.z + qr[t].w * kv.w;
      }
      sc[jj][h][ii] = acc * scl[h];
    }
    __syncthreads();
    float sv[JB1]; float cm = -FLT_MAX;
#pragma unroll
    for (int jj = 0; jj < JB1; ++jj) {
      const int jg = jb + jj;
      float s = 0.f;
#pragma unroll
      for (int h0 = 0; h0 < NH; ++h0) s += sc[jj][h0][ii] * pre[h0][h];
      s += relt[rel_bucket(i - jg)][h] * REL_SCALE;
      if (jg >= jhi || jg > i + MEM) s = -FLT_MAX;   // causal / split edge
      sv[jj] = s; cm = fmaxf(cm, s);
    }
    const float mn = fmaxf(m, cm);
    float ls = 0.f;
#pragma unroll
    for (int jj = 0; jj < JB1; ++jj) ls += expf(sv[jj] - mn);
    l = l * expf(m - mn) + ls;
    m = mn;
  }
  mpart[((size_t)c * NH + h) * N_SEQ + i] = m;
  lpart[((size_t)c * NH + h) * N_SEQ + i] = l;
}

// ---------------------------------------------------------------------------
// Merge partial (m,l) -> global (M,L) per (h,i)
// ---------------------------------------------------------------------------
__global__ __launch_bounds__(256) void merge_ml(
    const float* __restrict__ mpart, const float* __restrict__ lpart,
    float* __restrict__ Mf, float* __restrict__ Lf)
{
  const int t = blockIdx.x * 256 + threadIdx.x;   // [h][i]
  const int i = t & (N_SEQ - 1);
  const int h = t >> 11;
  const int lim = (i & ~15) + 32;
  float m = -FLT_MAX;
#pragma unroll
  for (int c = 0; c < C_SPLIT; ++c)
    if (c * JS < lim) m = fmaxf(m, mpart[((size_t)c * NH + h) * N_SEQ + i]);
  float l = 0.f;
#pragma unroll
  for (int c = 0; c < C_SPLIT; ++c)
    if (c * JS < lim) {
      float mc = mpart[((size_t)c * NH + h) * N_SEQ + i];
      l += lpart[((size_t)c * NH + h) * N_SEQ + i] * expf(mc - m);
    }
  Mf[t] = m;
  Lf[t] = l;
}

// ---------------------------------------------------------------------------
// Pass 2: normalized probs -> post_proj mix -> O accumulation per j-split.
// ---------------------------------------------------------------------------
#define JB2 4
__global__ __launch_bounds__(256) void attn_pass2(
    const float* __restrict__ qb, const float* __restrict__ kb,
    const float* __restrict__ vb,
    const float* __restrict__ pre_proj, const float* __restrict__ post_proj,
    const float* __restrict__ qk_scale, const float* __restrict__ rel_table,
    const float* __restrict__ Mfin, const float* __restrict__ Lfin,
    float* __restrict__ opart)
{
  const int i0 = blockIdx.x * 16;
  const int c = blockIdx.y;
  const int jlo = c * JS;
  if (jlo >= i0 + 32) return;
  const int jhi = min(jlo + JS, i0 + 32);   // JB2 | (jhi - jlo)
  const int tid = threadIdx.x;
  const int ii = tid & 15, h = tid >> 4;
  const int i = i0 + ii;

  __shared__ float k_lds[JB2][NH][DH + 4];
  __shared__ float v_lds[JB2][NH][DH + 4];
  __shared__ float sc[JB2][NH][16];
  __shared__ float pl[JB2][NH][16];
  __shared__ float pre[NH][NH], post[NH][NH];
  __shared__ float relt[NB][NH], scl[NH];

  pre[tid >> 4][tid & 15] = pre_proj[tid];
  post[tid >> 4][tid & 15] = post_proj[tid];
  for (int t = tid; t < NB * NH; t += 256) relt[t >> 4][t & 15] = rel_table[t];
  if (tid < NH) scl[tid] = 1.0f / fmaxf(expf(qk_scale[tid]), 0.01f);

  float4 qr[16];
  {
    const float4* qrow = (const float4*)(qb + ((size_t)h * N_SEQ + i) * DH);
#pragma unroll
    for (int t = 0; t < 16; ++t) qr[t] = qrow[t];
  }
  const float Mv = Mfin[h * N_SEQ + i];
  const float invL = 1.0f / Lfin[h * N_SEQ + i];

  float4 ov[16];
#pragma unroll
  for (int t = 0; t < 16; ++t) ov[t] = make_float4(0.f, 0.f, 0.f, 0.f);

  __syncthreads();

  for (int jb = jlo; jb < jhi; jb += JB2) {
    {
      const int hl = tid >> 4;
      const int x4 = (tid & 15) * 4;
#pragma unroll
      for (int w = 0; w < JB2; ++w) {
        const int jg = jb + w;
        *(float4*)&k_lds[w][hl][x4] =
            *(const float4*)(kb + ((size_t)hl * JTOT + jg) * DH + x4);
        *(float4*)&v_lds[w][hl][x4] =
            *(const float4*)(vb + ((size_t)hl * JTOT + jg) * DH + x4);
      }
    }
    __syncthreads();
#pragma unroll
    for (int jj = 0; jj < JB2; ++jj) {
      const float* kr = k_lds[jj][h];
      float acc = 0.f;
#pragma unroll
      for (int t = 0; t < 16; ++t) {
        float4 kv = *(const float4*)&kr[t * 4];
        acc += qr[t].x * kv.x + qr[t].y * kv.y + qr[t].z * kv.z + qr[t].w * kv.w;
      }
      sc[jj][h][ii] = acc * scl[h];
    }
    __syncthreads();
#pragma unroll
    for (int jj = 0; jj < JB2; ++jj) {
      const int jg = jb + jj;
      float s = 0.f;
#pragma unroll
      for (int h0 = 0; h0 < NH; ++h0) s += sc[jj][h0][ii] * pre[h0][h];
      s += relt[rel_bucket(i - jg)][h] * REL_SCALE;
      if (jg > i + MEM) s = -FLT_MAX;
      pl[jj][h][ii] = expf(s - Mv) * invL;
    }
    __syncthreads();
#pragma unroll
    for (int jj = 0; jj < JB2; ++jj) {
      float a = 0.f;
#pragma unroll
      for (int h1 = 0; h1 < NH; ++h1) a += pl[jj][h1][ii] * post[h1][h];
      const float* vr = v_lds[jj][h];
#pragma unroll
      for (int t = 0; t < 16; ++t) {
        float4 vv = *(const float4*)&vr[t * 4];
        ov[t].x += a * vv.x; ov[t].y += a * vv.y;
        ov[t].z += a * vv.z; ov[t].w += a * vv.w;
      }
    }
    __syncthreads();
  }
  float* od = opart + ((size_t)c * N_SEQ + i) * DIMN + h * DH;
#pragma unroll
  for (int t = 0; t < 16; ++t) *(float4*)(od + t * 4) = ov[t];
}

// ---------------------------------------------------------------------------
// Merge O partials -> ctx (row i, col h*64+d)
// ---------------------------------------------------------------------------
__global__ __launch_bounds__(256) void merge_ctx(
    const float* __restrict__ opart, float* __restrict__ ctx)
{
  const int t = blockIdx.x * 256 + threadIdx.x;   // over N*DIM/4
  const int i = t >> 8;                            // DIM/4 = 256
  const int c4 = t & 255;
  const int lim = (i & ~15) + 32;
  float4 acc = make_float4(0.f, 0.f, 0.f, 0.f);
#pragma unroll
  for (int c = 0; c < C_SPLIT; ++c) {
    if (c * JS < lim) {
      float4 v = ((const float4*)opart)[((size_t)c * N_SEQ + i) * 256 + c4];
      acc.x += v.x; acc.y += v.y; acc.z += v.z; acc.w += v.w;
    }
  }
  ((float4*)ctx)[(size_t)i * 256 + c4] = acc;
}

// ---------------------------------------------------------------------------
extern "C" void kernel_launch(void* const* d_in, const int* in_sizes, int n_in,
                              void* d_out, int out_size, void* d_ws, size_t ws_size,
                              hipStream_t stream)
{
  const float* x         = (const float*)d_in[0];
  const float* rot       = (const float*)d_in[1];
  const float* Wq        = (const float*)d_in[2];
  const float* Wk        = (const float*)d_in[3];
  const float* Wv        = (const float*)d_in[4];
  const float* Wo        = (const float*)d_in[5];
  const float* bo        = (const float*)d_in[6];
  const float* mem_k     = (const float*)d_in[7];
  const float* mem_v     = (const float*)d_in[8];
  const float* pre_proj  = (const float*)d_in[9];
  const float* post_proj = (const float*)d_in[10];
  const float* qk_scale  = (const float*)d_in[11];
  const float* rel_table = (const float*)d_in[12];
  float* out = (float*)d_out;
  float* ws  = (float*)d_ws;

  // workspace layout (floats); tmp aliases opart/ctx (disjoint live ranges)
  float* qb    = ws;                                   // 2,097,152
  float* kb    = qb + (size_t)NH * N_SEQ * DH;         // 2,113,536
  float* vb    = kb + (size_t)NH * JTOT * DH;          // 2,113,536
  float* mpart = vb + (size_t)NH * JTOT * DH;          // 131,072
  float* lpart = mpart + (size_t)C_SPLIT * NH * N_SEQ; // 131,072
  float* Mf    = lpart + (size_t)C_SPLIT * NH * N_SEQ; // 32,768
  float* Lf    = Mf + (size_t)NH * N_SEQ;              // 32,768
  float* region = Lf + (size_t)NH * N_SEQ;
  float* tmp   = region;                               // 3*N*DIM (early)
  float* opart = region;                               // C*N*DIM (late)
  float* ctx   = region + (size_t)C_SPLIT * N_SEQ * DIMN; // N*DIM
  (void)in_sizes; (void)n_in; (void)out_size; (void)ws_size;

  dim3 gB(DIMN / 64, N_SEQ / 64);
  gemm_f32<<<gB, 256, 0, stream>>>(x, Wq, tmp, nullptr, N_SEQ, DIMN, DIMN);
  gemm_f32<<<gB, 256, 0, stream>>>(x, Wk, tmp + (size_t)N_SEQ * DIMN, nullptr, N_SEQ, DIMN, DIMN);
  gemm_f32<<<gB, 256, 0, stream>>>(x, Wv, tmp + 2 * (size_t)N_SEQ * DIMN, nullptr, N_SEQ, DIMN, DIMN);

  postproc<<<(NH * N_SEQ + NH * MEM) / 4, 256, 0, stream>>>(tmp, rot, mem_k, mem_v, qb, kb, vb);

  attn_pass1<<<dim3(N_SEQ / 16, C_SPLIT), 256, 0, stream>>>(
      qb, kb, pre_proj, qk_scale, rel_table, mpart, lpart);
  merge_ml<<<NH * N_SEQ / 256, 256, 0, stream>>>(mpart, lpart, Mf, Lf);
  attn_pass2<<<dim3(N_SEQ / 16, C_SPLIT), 256, 0, stream>>>(
      qb, kb, vb, pre_proj, post_proj, qk_scale, rel_table, Mf, Lf, opart);
  merge_ctx<<<(N_SEQ * DIMN / 4) / 256, 256, 0, stream>>>(opart, ctx);

  gemm_f32<<<gB, 256, 0, stream>>>(ctx, Wo, out, bo, N_SEQ, DIMN, DIMN);
}